// Round 1
// baseline (204.328 us; speedup 1.0000x reference)
//
#include <hip/hip_runtime.h>

#define WIN 7
#define BB 64
#define HH 320
#define WW 320
#define OH 314
#define OW 314
#define TW 128            // output columns per block
#define NTHREADS 128
#define ROWS_PER_BAND 64  // output rows per block
#define NCOLT 3           // ceil(OW / TW)
#define NBANDS 5          // ceil(OH / ROWS_PER_BAND)
#define STAGE_STRIDE 136  // >= TW + WIN - 1 (=134), padded

__global__ __launch_bounds__(NTHREADS) void ssim_main(
    const float* __restrict__ X, const float* __restrict__ Y,
    const float* __restrict__ dr, double* __restrict__ acc)
{
    const int blk   = blockIdx.x;
    const int b     = blk / (NCOLT * NBANDS);
    const int rem   = blk % (NCOLT * NBANDS);
    const int ct    = rem / NBANDS;
    const int band  = rem % NBANDS;
    const int c0    = ct * TW;
    const int r0    = band * ROWS_PER_BAND;
    const int r1    = min(r0 + ROWS_PER_BAND, OH);   // exclusive out-row end
    const int tid   = threadIdx.x;

    // 5 moments: sx, sy, sxx, syy, sxy (channel-combined), double-buffered row stage
    __shared__ float qs[2][5][STAGE_STRIDE];
    __shared__ double wsum[NTHREADS / 64];

    const float d  = dr[b];
    const float C1 = (0.01f * d) * (0.01f * d);
    const float C2 = (0.03f * d) * (0.03f * d);

    const size_t planeHW = (size_t)HH * WW;
    const float* X0 = X + (size_t)b * 2 * planeHW;
    const float* X1 = X0 + planeHW;
    const float* Y0 = Y + (size_t)b * 2 * planeHW;
    const float* Y1 = Y0 + planeHW;

    const int cend     = min(c0 + TW + WIN - 1, WW); // exclusive input col end
    const int nOutCols = min(TW, OW - c0);
    const bool activeOut = (tid < nOutCols);

    // 7-row sliding window of horizontal sums, per moment
    float w0[5], w1[5], w2[5], w3[5], w4[5], w5[5], w6[5];
    float ssum = 0.f;
    int p = 0;

    for (int r = r0; r < r1 + WIN - 1; ++r) {
        // ---- stage row r: load 4 planes, combine channels into 5 moments ----
        for (int col = c0 + tid; col < cend; col += NTHREADS) {
            const int off = r * WW + col;
            const float x0 = X0[off], x1 = X1[off];
            const float y0 = Y0[off], y1 = Y1[off];
            const int j = col - c0;
            qs[p][0][j] = x0 + x1;
            qs[p][1][j] = y0 + y1;
            qs[p][2][j] = x0 * x0 + x1 * x1;
            qs[p][3][j] = y0 * y0 + y1 * y1;
            qs[p][4][j] = x0 * y0 + x1 * y1;
        }
        __syncthreads();

        // ---- horizontal 7-tap sums (always in-bounds of padded stage) ----
        float h[5];
        #pragma unroll
        for (int q = 0; q < 5; ++q) {
            float s = qs[p][q][tid];
            #pragma unroll
            for (int dc = 1; dc < WIN; ++dc) s += qs[p][q][tid + dc];
            h[q] = s;
        }
        p ^= 1;

        // ---- shift vertical register window ----
        #pragma unroll
        for (int q = 0; q < 5; ++q) {
            w0[q] = w1[q]; w1[q] = w2[q]; w2[q] = w3[q];
            w3[q] = w4[q]; w4[q] = w5[q]; w5[q] = w6[q];
            w6[q] = h[q];
        }

        // ---- emit SSIM once window is full ----
        if (r - r0 >= WIN - 1 && activeOut) {
            float v[5];
            #pragma unroll
            for (int q = 0; q < 5; ++q)
                v[q] = ((w0[q] + w1[q]) + (w2[q] + w3[q])) + ((w4[q] + w5[q]) + w6[q]);
            const float inv = 1.0f / 49.0f;
            const float cn  = 49.0f / 48.0f;
            const float ux  = v[0] * inv, uy  = v[1] * inv;
            const float uxx = v[2] * inv, uyy = v[3] * inv, uxy = v[4] * inv;
            const float vx  = cn * (uxx - ux * ux);
            const float vy  = cn * (uyy - uy * uy);
            const float vxy = cn * (uxy - ux * uy);
            const float A1  = 2.f * ux * uy + C1;
            const float A2  = 2.f * vxy + C2;
            const float B1  = ux * ux + uy * uy + C1;
            const float B2  = vx + vy + C2;
            ssum += (A1 * A2) / (B1 * B2);
        }
    }

    // ---- reduction: wave shuffle (double) -> LDS -> one atomic per block ----
    double local = (double)ssum;
    #pragma unroll
    for (int off = 32; off > 0; off >>= 1)
        local += __shfl_down(local, off, 64);
    if ((tid & 63) == 0) wsum[tid >> 6] = local;
    __syncthreads();
    if (tid == 0) {
        double tot = wsum[0];
        #pragma unroll
        for (int i = 1; i < NTHREADS / 64; ++i) tot += wsum[i];
        atomicAdd(acc, tot);
    }
}

__global__ void ssim_final(const double* __restrict__ acc, float* __restrict__ out)
{
    const double N = (double)BB * (double)OH * (double)OW;
    out[0] = (float)(1.0 - acc[0] / N);
}

extern "C" void kernel_launch(void* const* d_in, const int* in_sizes, int n_in,
                              void* d_out, int out_size, void* d_ws, size_t ws_size,
                              hipStream_t stream)
{
    const float* X  = (const float*)d_in[0];
    const float* Y  = (const float*)d_in[1];
    const float* dr = (const float*)d_in[2];
    // d_in[3] is the box kernel w (all 1/49) — folded into constants.
    double* acc = (double*)d_ws;
    float*  out = (float*)d_out;

    hipMemsetAsync(d_ws, 0, sizeof(double), stream);
    ssim_main<<<dim3(BB * NCOLT * NBANDS), dim3(NTHREADS), 0, stream>>>(X, Y, dr, acc);
    ssim_final<<<dim3(1), dim3(1), 0, stream>>>(acc, out);
}

// Round 2
// 168.112 us; speedup vs baseline: 1.2154x; 1.2154x over previous
//
#include <hip/hip_runtime.h>

#define WW 320          // input width/height
#define OWID 314        // output cols
#define OHEI 314        // output rows
#define BB 64           // batch
#define RPB 16          // output rows per band
#define NBAND 20        // ceil(314/16)
#define NSTRIP 79       // ceil(314/4) output-col strips of 4
#define NTH 256
#define NBLK ((BB * NBAND * NSTRIP) / NTH)   // 64*20*79/256 = 395 exactly

// Compute the 4 horizontal 7-tap sums of the 5 channel-combined moments for
// one input row. h[q*4+j] for moment q in {sx,sy,sxx,syy,sxy}, output col j.
__device__ __forceinline__ void compute_h(
    const float* __restrict__ X0, const float* __restrict__ X1,
    const float* __restrict__ Y0, const float* __restrict__ Y1,
    int off, int o2, float h[20])
{
    float4 ax0 = *(const float4*)(X0 + off);
    float4 ax1 = *(const float4*)(X0 + off + 4);
    float4 ax2 = *(const float4*)(X0 + off + o2);
    float4 bx0 = *(const float4*)(X1 + off);
    float4 bx1 = *(const float4*)(X1 + off + 4);
    float4 bx2 = *(const float4*)(X1 + off + o2);
    float4 ay0 = *(const float4*)(Y0 + off);
    float4 ay1 = *(const float4*)(Y0 + off + 4);
    float4 ay2 = *(const float4*)(Y0 + off + o2);
    float4 by0 = *(const float4*)(Y1 + off);
    float4 by1 = *(const float4*)(Y1 + off + 4);
    float4 by2 = *(const float4*)(Y1 + off + o2);

    float x0[10] = {ax0.x, ax0.y, ax0.z, ax0.w, ax1.x, ax1.y, ax1.z, ax1.w, ax2.x, ax2.y};
    float x1[10] = {bx0.x, bx0.y, bx0.z, bx0.w, bx1.x, bx1.y, bx1.z, bx1.w, bx2.x, bx2.y};
    float y0[10] = {ay0.x, ay0.y, ay0.z, ay0.w, ay1.x, ay1.y, ay1.z, ay1.w, ay2.x, ay2.y};
    float y1[10] = {by0.x, by0.y, by0.z, by0.w, by1.x, by1.y, by1.z, by1.w, by2.x, by2.y};

    float sx[10], sy[10], sxx[10], syy[10], sxy[10];
    #pragma unroll
    for (int j = 0; j < 10; ++j) {
        sx[j]  = x0[j] + x1[j];
        sy[j]  = y0[j] + y1[j];
        sxx[j] = x0[j] * x0[j] + x1[j] * x1[j];
        syy[j] = y0[j] * y0[j] + y1[j] * y1[j];
        sxy[j] = x0[j] * y0[j] + x1[j] * y1[j];
    }
    #pragma unroll
    for (int q = 0; q < 5; ++q) {
        const float* m = (q == 0) ? sx : (q == 1) ? sy : (q == 2) ? sxx : (q == 3) ? syy : sxy;
        float t0 = ((m[0] + m[1]) + (m[2] + m[3])) + ((m[4] + m[5]) + m[6]);
        float t1 = t0 - m[0] + m[7];
        float t2 = t1 - m[1] + m[8];
        float t3 = t2 - m[2] + m[9];
        h[q * 4 + 0] = t0; h[q * 4 + 1] = t1; h[q * 4 + 2] = t2; h[q * 4 + 3] = t3;
    }
}

__global__ __launch_bounds__(NTH) void ssim_main(
    const float* __restrict__ X, const float* __restrict__ Y,
    const float* __restrict__ dr, double* __restrict__ acc,
    unsigned* __restrict__ counter, float* __restrict__ out)
{
    const int wi   = blockIdx.x * NTH + threadIdx.x;   // grid sized exactly
    const int s    = wi % NSTRIP;
    const int g    = wi / NSTRIP;
    const int band = g % NBAND;
    const int b    = g / NBAND;
    const int r0   = band * RPB;
    const int r1   = min(r0 + RPB, OHEI);
    const int cb   = s * 4;
    const int o2   = (cb <= 308) ? 8 : 4;   // clamp 3rd float4 for last strip

    const size_t plane = (size_t)WW * WW;
    const float* X0 = X + (size_t)b * 2 * plane;
    const float* X1 = X0 + plane;
    const float* Y0 = Y + (size_t)b * 2 * plane;
    const float* Y1 = Y0 + plane;

    const float d  = dr[b];
    const float C1 = (0.01f * d) * (0.01f * d);
    const float C2 = (0.03f * d) * (0.03f * d);

    float cm[4];
    #pragma unroll
    for (int j = 0; j < 4; ++j) cm[j] = (cb + j < OWID) ? 1.0f : 0.0f;

    float v[20];
    #pragma unroll
    for (int i = 0; i < 20; ++i) v[i] = 0.0f;

    // warm-up: rows r0 .. r0+5
    for (int k = 0; k < 6; ++k) {
        float h[20];
        compute_h(X0, X1, Y0, Y1, (r0 + k) * WW + cb, o2, h);
        #pragma unroll
        for (int i = 0; i < 20; ++i) v[i] += h[i];
    }

    float ssum = 0.0f;
    for (int t = r0; t < r1; ++t) {
        float hn[20];
        compute_h(X0, X1, Y0, Y1, (t + 6) * WW + cb, o2, hn);
        #pragma unroll
        for (int i = 0; i < 20; ++i) v[i] += hn[i];

        const float inv = 1.0f / 49.0f;
        const float cn  = 49.0f / 48.0f;
        #pragma unroll
        for (int j = 0; j < 4; ++j) {
            float ux  = v[j]      * inv, uy  = v[4 + j]  * inv;
            float uxx = v[8 + j]  * inv, uyy = v[12 + j] * inv, uxy = v[16 + j] * inv;
            float vx  = cn * (uxx - ux * ux);
            float vy  = cn * (uyy - uy * uy);
            float vxy = cn * (uxy - ux * uy);
            float A1  = 2.0f * ux * uy + C1;
            float A2  = 2.0f * vxy + C2;
            float B1  = ux * ux + uy * uy + C1;
            float B2  = vx + vy + C2;
            ssum += cm[j] * (A1 * A2) / (B1 * B2);
        }

        float ho[20];
        compute_h(X0, X1, Y0, Y1, t * WW + cb, o2, ho);
        #pragma unroll
        for (int i = 0; i < 20; ++i) v[i] -= ho[i];
    }

    // ---- reduction: wave shuffle (double) -> LDS -> one atomic per block ----
    double local = (double)ssum;
    #pragma unroll
    for (int off = 32; off > 0; off >>= 1)
        local += __shfl_down(local, off, 64);
    __shared__ double wsum[NTH / 64];
    const int lane = threadIdx.x & 63, wid = threadIdx.x >> 6;
    if (lane == 0) wsum[wid] = local;
    __syncthreads();
    if (threadIdx.x == 0) {
        double tot = (wsum[0] + wsum[1]) + (wsum[2] + wsum[3]);
        atomicAdd(acc, tot);
        __threadfence();
        unsigned ticket = atomicAdd(counter, 1u);
        if (ticket == NBLK - 1) {
            double stot = atomicAdd(acc, 0.0);   // device-scope coherent read
            const double N = (double)BB * (double)OHEI * (double)OWID;
            out[0] = (float)(1.0 - stot / N);
        }
    }
}

extern "C" void kernel_launch(void* const* d_in, const int* in_sizes, int n_in,
                              void* d_out, int out_size, void* d_ws, size_t ws_size,
                              hipStream_t stream)
{
    const float* X  = (const float*)d_in[0];
    const float* Y  = (const float*)d_in[1];
    const float* dr = (const float*)d_in[2];
    // d_in[3] is the box kernel w (all 1/49) — folded into constants.
    double*   acc     = (double*)d_ws;
    unsigned* counter = (unsigned*)((char*)d_ws + 8);
    float*    out     = (float*)d_out;

    hipMemsetAsync(d_ws, 0, 16, stream);
    ssim_main<<<dim3(NBLK), dim3(NTH), 0, stream>>>(X, Y, dr, acc, counter, out);
}